// Round 9
// baseline (17237.544 us; speedup 1.0000x reference)
//
#include <hip/hip_runtime.h>

// ---------------------------------------------------------------------------
// KokoroModel: emb -> biLSTM enc -> proj -> dur MLP -> length-regulate ->
//              MHA (teacher-forced) -> dec LSTM -> mel proj
// B=8, T_TEXT=256, T_MEL=1024, H=512, MEL=80, NH=8, HD=64 — all fp32.
// Round 9: revert r8's single-XCD experiment (plain-store visibility failed:
// hang-valves + stale h). Back to the proven sc1 exchange, restructured as
// 2 batch-split groups of 16 wgs per scan: wg owns 32 j x 4 gates x 4
// batches; staging requests, barrier participants, LDS reads all halved.
// ---------------------------------------------------------------------------

typedef unsigned short u16;
typedef unsigned int u32;
typedef float f4 __attribute__((ext_vector_type(4)));

#define BB 8
#define TT 256
#define TM 1024
#define HH 512
#define MELC 80
#define G4 2048   // 4*H

__device__ __forceinline__ float sigmoidf_(float x) { return 1.f / (1.f + __expf(-x)); }
__device__ __forceinline__ float tanh_fast(float x) {
    float e = __expf(2.f * x);
    return 1.f - 2.f / (e + 1.f);
}

// ------------------------- workspace layout (floats) -----------------------
// O_ENCH: enc h ping-pong, 4 groups x [2 slots][4][512] = 16384
// O_DECH: dec h ping-pong, 2 groups x [2 slots][4][512] = 8192
// O_CNT : sync ints — enc: 4 groups x 1024 @0; dec: 2 groups x 1024 @6144
#define O_ENCH    0u
#define O_DECH    16384u
#define O_CNT     24576u            /* ints, 12288 (ends at 36864) */
#define O_LOGDUR  36864u
#define O_KIDX    38912u            /* 8192 ints */
#define O_ENC     47104u            /* 2048x512 */
#define O_R1      1095680u          /* 4M: hf|hb|cat  -> exp -> ctx */
#define O_ATT     5289984u          /* 4M attended */
#define O_QIN     9484288u          /* 4M q_in */
#define O_BIG2    13678592u         /* 8M: q|k -> dec_in -> h_dec|mel_f */
#define O_BIG1    22067200u         /* 16.8M: xg_f|xg_b|x -> h1|h2|v|mel_in -> xg_dec */
// sub-offsets
#define O_HF      (O_R1)
#define O_HB      (O_R1 + 1048576u)
#define O_CAT     (O_R1 + 2097152u)
#define O_EXP     (O_R1)
#define O_CTX     (O_R1)
#define O_Q       (O_BIG2)
#define O_K       (O_BIG2 + 4194304u)
#define O_DECIN   (O_BIG2)
#define O_HDEC    (O_BIG2)
#define O_MELF    (O_BIG2 + 4194304u)
#define O_XGF     (O_BIG1)
#define O_XGB     (O_BIG1 + 4194304u)
#define O_X       (O_BIG1 + 8388608u)
#define O_H1      (O_BIG1 + 8388608u)
#define O_H2      (O_BIG1 + 9437184u)
#define O_V       (O_BIG1 + 10485760u)
#define O_MELIN   (O_BIG1 + 14680064u)
#define O_XGD     (O_BIG1)

// ---------------------------------------------------------------------------
__global__ __launch_bounds__(256) void zero_kernel(float* p, int n) {
    int i = blockIdx.x * 256 + threadIdx.x;
    if (i < n) p[i] = 0.f;
}

__global__ __launch_bounds__(256) void embed_kernel(const int* idx, const float* emb, float* x) {
    int i = blockIdx.x * 256 + threadIdx.x;      // over 2048*512
    int tok = i >> 9, h = i & 511;
    x[i] = emb[(size_t)idx[tok] * HH + h];
}

// C[M,N] = act(A[M,K] @ W[N,K]^T + bias[N]);  all fp32.
// 128x128 tile, BK=16, 256 threads, 8x8 micro-tile in 2x2 float4 fragments.
template <int ACT>
__global__ __launch_bounds__(256) void gemm_bt(const float* __restrict__ A,
                                               const float* __restrict__ W,
                                               const float* __restrict__ bias,
                                               float* __restrict__ C,
                                               int M, int N, int K) {
    __shared__ float As[16][132];
    __shared__ float Ws[16][132];
    const int bm = blockIdx.y * 128, bn = blockIdx.x * 128;
    const int tid = threadIdx.x;
    const int tx = tid & 15, ty = tid >> 4;
    float acc[64];
#pragma unroll
    for (int i = 0; i < 64; i++) acc[i] = 0.f;

    for (int k0 = 0; k0 < K; k0 += 16) {
#pragma unroll
        for (int q = 0; q < 2; q++) {
            int fid = tid * 2 + q;               // 0..511
            int m = fid >> 2, kq = (fid & 3) << 2;
            float4 va = *(const float4*)(A + (size_t)(bm + m) * K + k0 + kq);
            As[kq + 0][m] = va.x; As[kq + 1][m] = va.y;
            As[kq + 2][m] = va.z; As[kq + 3][m] = va.w;
            float4 vw = make_float4(0.f, 0.f, 0.f, 0.f);
            if (bn + m < N) vw = *(const float4*)(W + (size_t)(bn + m) * K + k0 + kq);
            Ws[kq + 0][m] = vw.x; Ws[kq + 1][m] = vw.y;
            Ws[kq + 2][m] = vw.z; Ws[kq + 3][m] = vw.w;
        }
        __syncthreads();
#pragma unroll
        for (int kk = 0; kk < 16; kk++) {
            float4 a0 = *(const float4*)&As[kk][ty * 4];
            float4 a1 = *(const float4*)&As[kk][64 + ty * 4];
            float4 b0 = *(const float4*)&Ws[kk][tx * 4];
            float4 b1 = *(const float4*)&Ws[kk][64 + tx * 4];
            float av[8] = {a0.x, a0.y, a0.z, a0.w, a1.x, a1.y, a1.z, a1.w};
            float bv[8] = {b0.x, b0.y, b0.z, b0.w, b1.x, b1.y, b1.z, b1.w};
#pragma unroll
            for (int ih = 0; ih < 2; ih++)
#pragma unroll
                for (int ii = 0; ii < 4; ii++) {
                    float a = av[ih * 4 + ii];
#pragma unroll
                    for (int jh = 0; jh < 2; jh++)
#pragma unroll
                        for (int jjv = 0; jjv < 4; jjv++)
                            acc[(ih * 2 + jh) * 16 + ii * 4 + jjv] =
                                fmaf(a, bv[jh * 4 + jjv], acc[(ih * 2 + jh) * 16 + ii * 4 + jjv]);
                }
        }
        __syncthreads();
    }
#pragma unroll
    for (int ih = 0; ih < 2; ih++)
#pragma unroll
        for (int jh = 0; jh < 2; jh++) {
            int n = bn + jh * 64 + tx * 4;
            if (n >= N) continue;
            float4 bb = make_float4(0.f, 0.f, 0.f, 0.f);
            if (bias) bb = *(const float4*)(bias + n);
#pragma unroll
            for (int ii = 0; ii < 4; ii++) {
                int m = bm + ih * 64 + ty * 4 + ii;
                float4 o;
                o.x = acc[(ih * 2 + jh) * 16 + ii * 4 + 0] + bb.x;
                o.y = acc[(ih * 2 + jh) * 16 + ii * 4 + 1] + bb.y;
                o.z = acc[(ih * 2 + jh) * 16 + ii * 4 + 2] + bb.z;
                o.w = acc[(ih * 2 + jh) * 16 + ii * 4 + 3] + bb.w;
                if (ACT == 1) {
                    o.x = fmaxf(o.x, 0.f); o.y = fmaxf(o.y, 0.f);
                    o.z = fmaxf(o.z, 0.f); o.w = fmaxf(o.w, 0.f);
                }
                *(float4*)(C + (size_t)m * N + n) = o;
            }
        }
}

// ---------------------------------------------------------------------------
// Persistent fence-free LSTM scan, batch-split. ngroup = ndir*2 groups of 16
// wgs. Group = (dir, half): handles batches [half*4, half*4+4) full-H. wg owns
// 32 j x 4 gates; wave owns 8 j (2 quads); lane: gate=lane&3, ks=lane>>2
// (32 k's). Weights wv[2][4][8] float4 in VGPRs (256 f/lane). h exchange: sc1
// stores + dwordx4 sc0 sc1 staging (8KB/wg) -> LDS bank-rotated. Barrier:
// 16 spread flags, flat ballot poll; xg prefetch hidden under the wait.
__global__ __launch_bounds__(256, 1) void lstm_scan(
    const float* __restrict__ xg0, const float* __restrict__ xg1,
    const float* __restrict__ whh0, const float* __restrict__ whh1,
    const float* __restrict__ bhh0, const float* __restrict__ bhh1,
    float* hbuf, float* hout0, float* hout1,
    int* sync, int T, int ndir) {
    const int wg = blockIdx.x;
    const int group = wg >> 4;
    const int wgi = wg & 15;
    const int dir = (ndir == 2) ? (group >> 1) : 0;
    const int half = group & 1;
    const float* xg  = dir ? xg1 : xg0;
    const float* whh = dir ? whh1 : whh0;
    const float* bhh = dir ? bhh1 : bhh0;
    float* hout = dir ? hout1 : hout0;
    float* hb = hbuf + group * 4096;             // [2 slots][4][512]
    int* syn = sync + group * 1024;              // flag at wgi*64

    const int wave = threadIdx.x >> 6;
    const int lane = threadIdx.x & 63;
    const int gate = lane & 3;
    const int ks = lane >> 2;                    // k-slice of 32
    const int jbase = wgi * 32 + wave * 8;       // 8 j's per wave (2 quads)

    // weights: wv[q][jj][i4] = W_hh[gate*512 + jbase+q*4+jj][ks*32 + i4*4 ..)
    float4 wv[2][4][8];
    float xb[2][4];
#pragma unroll
    for (int q = 0; q < 2; q++)
#pragma unroll
        for (int jj = 0; jj < 4; jj++) {
            int row = gate * HH + jbase + q * 4 + jj;
            const float4* wp = (const float4*)(whh + (size_t)row * HH + ks * 32);
#pragma unroll
            for (int i = 0; i < 8; i++) wv[q][jj][i] = wp[i];
            xb[q][jj] = bhh[row];
        }
    float c_ = 0.f;                              // owner-lane cell state

    __shared__ float hs[2048];                   // staged h (4 batches), rotated

    // prefetch xg for t=0 (ks==0 lanes)
    float4 xgv[2][4];
    if (ks == 0) {
        const int te0 = dir ? (T - 1) : 0;
#pragma unroll
        for (int q = 0; q < 2; q++)
#pragma unroll
            for (int b = 0; b < 4; b++) {
                int gb = half * 4 + b;
                xgv[q][b] = *(const float4*)(xg + (size_t)(gb * T + te0) * G4
                                             + gate * HH + jbase + q * 4);
            }
    }

    for (int t = 0; t < T; t++) {
        const int te = dir ? (T - 1 - t) : t;
        // stage h_prev: 2 x dwordx4 sc0 sc1 per thread -> LDS (bank-rotated)
        const float* hg = hb + ((t + 1) & 1) * 2048;
        f4 hv[2];
#pragma unroll
        for (int q = 0; q < 2; q++) {
            const float* ap = hg + ((q * 256 + threadIdx.x) << 2);
            asm volatile("global_load_dwordx4 %0, %1, off sc0 sc1"
                         : "=v"(hv[q]) : "v"(ap) : "memory");
        }
        __builtin_amdgcn_s_waitcnt(0);
#pragma unroll
        for (int q = 0; q < 2; q++) {
            int flat = (q * 256 + threadIdx.x) << 2;
            int bb = flat >> 9, kk = flat & 511;
            int blk = kk >> 5, off = kk & 31;
            *(f4*)&hs[bb * HH + blk * 32 + ((off + (blk << 2)) & 31)] = hv[q];
        }
        __syncthreads();

        float hw_mine = 0.f;
#pragma unroll
        for (int b = 0; b < 4; b++) {
            float a[2][4];
            if (ks == 0) {
#pragma unroll
                for (int q = 0; q < 2; q++) {
                    a[q][0] = xgv[q][b].x + xb[q][0];
                    a[q][1] = xgv[q][b].y + xb[q][1];
                    a[q][2] = xgv[q][b].z + xb[q][2];
                    a[q][3] = xgv[q][b].w + xb[q][3];
                }
            } else {
#pragma unroll
                for (int q = 0; q < 2; q++)
#pragma unroll
                    for (int jj = 0; jj < 4; jj++) a[q][jj] = 0.f;
            }
#pragma unroll
            for (int i4 = 0; i4 < 8; i4++) {
                const float4 h4 = *(const float4*)
                    &hs[b * HH + ks * 32 + (((i4 + ks) & 7) << 2)];
#pragma unroll
                for (int q = 0; q < 2; q++)
#pragma unroll
                    for (int jj = 0; jj < 4; jj++) {
                        a[q][jj] = fmaf(wv[q][jj][i4].x, h4.x, a[q][jj]);
                        a[q][jj] = fmaf(wv[q][jj][i4].y, h4.y, a[q][jj]);
                        a[q][jj] = fmaf(wv[q][jj][i4].z, h4.z, a[q][jj]);
                        a[q][jj] = fmaf(wv[q][jj][i4].w, h4.w, a[q][jj]);
                    }
            }
            // reduce over ks (lane bits 2..5)
#pragma unroll
            for (int q = 0; q < 2; q++)
#pragma unroll
                for (int jj = 0; jj < 4; jj++) {
                    a[q][jj] += __shfl_xor(a[q][jj], 4);
                    a[q][jj] += __shfl_xor(a[q][jj], 8);
                    a[q][jj] += __shfl_xor(a[q][jj], 16);
                    a[q][jj] += __shfl_xor(a[q][jj], 32);
                }
            // owner (b,q,jj) = lane b*8+q*4+jj; gates from lanes base+0..3
#pragma unroll
            for (int q = 0; q < 2; q++) {
                const int base = b * 8 + q * 4;
                float gi_ = 0.f, gf_ = 0.f, gg_ = 0.f, go_ = 0.f;
                bool own = false;
#pragma unroll
                for (int jj = 0; jj < 4; jj++) {
                    float v = a[q][jj];
                    float g0 = __shfl(v, base + 0);
                    float g1 = __shfl(v, base + 1);
                    float g2 = __shfl(v, base + 2);
                    float g3 = __shfl(v, base + 3);
                    if (lane == base + jj) { gi_ = g0; gf_ = g1; gg_ = g2; go_ = g3; own = true; }
                }
                if (own) {
                    float i_ = sigmoidf_(gi_), f_ = sigmoidf_(gf_);
                    float G_ = tanh_fast(gg_), o_ = sigmoidf_(go_);
                    c_ = f_ * c_ + i_ * G_;
                    hw_mine = o_ * tanh_fast(c_);
                }
            }
        }
        // write h (sc1) + hout; lanes 0..31: b=lane>>3, j=jbase+(lane&7)
        if (lane < 32) {
            int b = lane >> 3, j = jbase + (lane & 7);
            __hip_atomic_store(hb + (t & 1) * 2048 + b * HH + j, hw_mine,
                               __ATOMIC_RELAXED, __HIP_MEMORY_SCOPE_AGENT);
            int gb = half * 4 + b;
            hout[(size_t)(gb * T + te) * HH + j] = hw_mine;
        }
        __builtin_amdgcn_s_waitcnt(0);           // h stores acked at coherence pt
        __syncthreads();
        const int need = t + 1;
        if (threadIdx.x == 0)
            __hip_atomic_store(syn + wgi * 64, need, __ATOMIC_RELAXED, __HIP_MEMORY_SCOPE_AGENT);
        // prefetch next step's xg while waiting on the barrier
        if (ks == 0 && t + 1 < T) {
            const int teN = dir ? (T - 2 - t) : (t + 1);
#pragma unroll
            for (int q = 0; q < 2; q++)
#pragma unroll
                for (int b = 0; b < 4; b++) {
                    int gb = half * 4 + b;
                    xgv[q][b] = *(const float4*)(xg + (size_t)(gb * T + teN) * G4
                                                 + gate * HH + jbase + q * 4);
                }
        }
        // flat all-to-all: wave0 polls the 16 spread flags
        if (wave == 0) {
            int it = 0;
            while (true) {
                int v = (lane < 16)
                    ? __hip_atomic_load(syn + lane * 64, __ATOMIC_RELAXED, __HIP_MEMORY_SCOPE_AGENT)
                    : need;
                unsigned long long mset = __ballot(v >= need);
                if ((mset & 0xFFFFull) == 0xFFFFull) break;
                __builtin_amdgcn_s_sleep(1);
                if (++it > (1 << 24)) break;     // safety valve
            }
        }
        __syncthreads();
    }
}

__global__ __launch_bounds__(256) void cat_kernel(const float* hf, const float* hb, float* cat) {
    int i = blockIdx.x * 256 + threadIdx.x;      // over 2048*1024
    int row = i >> 10, h = i & 1023;
    cat[i] = (h < HH) ? hf[(size_t)row * HH + h] : hb[(size_t)row * HH + h - HH];
}

__global__ __launch_bounds__(256) void dur3_kernel(const float* __restrict__ h2,
                                                   const float* __restrict__ w,
                                                   const float* __restrict__ b, float* out) {
    int row = blockIdx.x * 256 + threadIdx.x;    // 2048
    float acc = b[0];
    const float* hp = h2 + (size_t)row * 256;
    for (int k = 0; k < 256; k++) acc += hp[k] * w[k];
    out[row] = acc;
}

// durations -> cumsum -> searchsorted index per mel position (-1 = pad)
__global__ __launch_bounds__(256) void length_reg_kernel(const float* __restrict__ dur, int* kidx) {
    int b = blockIdx.x;
    int t = threadIdx.x;
    __shared__ int cum[256];
    cum[t] = (int)rintf(dur[b * TT + t]);
    __syncthreads();
    for (int off = 1; off < 256; off <<= 1) {
        int val = (t >= off) ? cum[t - off] : 0;
        __syncthreads();
        cum[t] += val;
        __syncthreads();
    }
    int total = cum[255];
    for (int pos = t; pos < TM; pos += 256) {
        int lo = 0, hi = 256;
        while (lo < hi) {
            int mid = (lo + hi) >> 1;
            if (cum[mid] <= pos) lo = mid + 1; else hi = mid;
        }
        int idx = (pos < total) ? ((lo < 255) ? lo : 255) : -1;
        kidx[b * TM + pos] = idx;
    }
}

__global__ __launch_bounds__(256) void expand_kernel(const float* __restrict__ enc,
                                                     const int* __restrict__ kidx, float* exp_) {
    int i = blockIdx.x * 256 + threadIdx.x;      // over 8192*512
    int row = i >> 9, h = i & 511;               // row = b*1024 + pos
    int b = row >> 10;
    int id = kidx[row];
    exp_[i] = (id >= 0) ? enc[(size_t)(b * TT + id) * HH + h] : 0.f;
}

__global__ __launch_bounds__(256) void melin_kernel(const float* __restrict__ mel, float* mel_in) {
    int i = blockIdx.x * 256 + threadIdx.x;      // over 8192*80
    if (i >= BB * TM * MELC) return;
    int row = i / MELC, cc = i - row * MELC;
    int b = row >> 10, tpos = row & 1023;
    mel_in[i] = (tpos == 0) ? 0.f : mel[(size_t)(b * TM + tpos - 1) * MELC + cc];
}

// Flash-style MHA: one q-row per thread; K/V tiles (32x64) in LDS.
__global__ __launch_bounds__(256) void attn_kernel(const float* __restrict__ q,
                                                   const float* __restrict__ k,
                                                   const float* __restrict__ v,
                                                   const int* __restrict__ kidx,
                                                   float* __restrict__ ctx) {
    const int bh = blockIdx.y;
    const int b = bh >> 3, h = bh & 7;
    const int qrow = blockIdx.x * 256 + threadIdx.x;
    __shared__ float Ks[32][64];
    __shared__ float Vs[32][64];
    __shared__ float spad[32];

    float qr[64], acc[64];
    const float* qp = q + (size_t)(b * TM + qrow) * HH + h * 64;
#pragma unroll
    for (int d = 0; d < 64; d++) qr[d] = qp[d] * 0.125f;
#pragma unroll
    for (int d = 0; d < 64; d++) acc[d] = 0.f;
    float m = -1e30f, l = 0.f;

    for (int k0 = 0; k0 < TM; k0 += 32) {
        __syncthreads();
#pragma unroll
        for (int i = 0; i < 8; i++) {
            int idx = threadIdx.x + i * 256;     // 0..2047
            int r = idx >> 6, d = idx & 63;
            size_t off = (size_t)(b * TM + k0 + r) * HH + h * 64 + d;
            Ks[r][d] = k[off];
            Vs[r][d] = v[off];
        }
        if (threadIdx.x < 32)
            spad[threadIdx.x] = (kidx[b * TM + k0 + threadIdx.x] < 0) ? 1.f : 0.f;
        __syncthreads();
        for (int r = 0; r < 32; r++) {
            float s = 0.f;
#pragma unroll
            for (int d = 0; d < 64; d++) s += qr[d] * Ks[r][d];
            if (spad[r] != 0.f) s = -1e9f;
            float mn = fmaxf(m, s);
            float corr = __expf(m - mn);
            float p = __expf(s - mn);
            l = l * corr + p;
#pragma unroll
            for (int d = 0; d < 64; d++) acc[d] = acc[d] * corr + p * Vs[r][d];
            m = mn;
        }
    }
    float inv = 1.f / l;
    float* op = ctx + (size_t)(b * TM + qrow) * HH + h * 64;
#pragma unroll
    for (int d = 0; d < 64; d++) op[d] = acc[d] * inv;
}

__global__ __launch_bounds__(256) void decin_kernel(const float* q_in, const float* att, float* dec_in) {
    int i = blockIdx.x * 256 + threadIdx.x;      // over 8192*1024
    int row = i >> 10, h = i & 1023;
    dec_in[i] = (h < HH) ? q_in[(size_t)row * HH + h] : att[(size_t)row * HH + h - HH];
}

__global__ __launch_bounds__(256) void finalize_kernel(const float* melf, const float* logdur, float* out) {
    int i = blockIdx.x * 256 + threadIdx.x;
    if (i < BB * TM * MELC) out[i] = melf[i];
    else if (i < BB * TM * MELC + BB * TT) out[i] = logdur[i - BB * TM * MELC];
}

// ---------------------------------------------------------------------------
extern "C" void kernel_launch(void* const* d_in, const int* in_sizes, int n_in,
                              void* d_out, int out_size, void* d_ws, size_t ws_size,
                              hipStream_t stream) {
    const int*   ph      = (const int*)d_in[0];
    const float* mel     = (const float*)d_in[1];
    const float* durs    = (const float*)d_in[2];
    const float* emb     = (const float*)d_in[3];
    const float* w_ih_f  = (const float*)d_in[4];
    const float* w_hh_f  = (const float*)d_in[5];
    const float* b_ih_f  = (const float*)d_in[6];
    const float* b_hh_f  = (const float*)d_in[7];
    const float* w_ih_b  = (const float*)d_in[8];
    const float* w_hh_b  = (const float*)d_in[9];
    const float* b_ih_b  = (const float*)d_in[10];
    const float* b_hh_b  = (const float*)d_in[11];
    const float* proj_w  = (const float*)d_in[12];
    const float* proj_b  = (const float*)d_in[13];
    const float* dur_w1  = (const float*)d_in[14];
    const float* dur_b1  = (const float*)d_in[15];
    const float* dur_w2  = (const float*)d_in[16];
    const float* dur_b2  = (const float*)d_in[17];
    const float* dur_w3  = (const float*)d_in[18];
    const float* dur_b3  = (const float*)d_in[19];
    const float* melin_w = (const float*)d_in[20];
    const float* melin_b = (const float*)d_in[21];
    const float* attin_w = (const float*)d_in[22];
    const float* attin_b = (const float*)d_in[23];
    const float* atout_w = (const float*)d_in[24];
    const float* atout_b = (const float*)d_in[25];
    const float* dec_wih = (const float*)d_in[26];
    const float* dec_whh = (const float*)d_in[27];
    const float* dec_bih = (const float*)d_in[28];
    const float* dec_bhh = (const float*)d_in[29];
    const float* melo_w  = (const float*)d_in[30];
    const float* melo_b  = (const float*)d_in[31];

    float* ws = (float*)d_ws;
    int*   kidx = (int*)(ws + O_KIDX);
    int*   cnts = (int*)(ws + O_CNT);

    dim3 b256(256);
    auto gemm = [&](const float* A, const float* W, const float* bias, float* C,
                    int M, int N, int K, int act) {
        dim3 g((N + 127) / 128, (M + 127) / 128);
        if (act) gemm_bt<1><<<g, b256, 0, stream>>>(A, W, bias, C, M, N, K);
        else     gemm_bt<0><<<g, b256, 0, stream>>>(A, W, bias, C, M, N, K);
    };

    // 0) zero scan h-buffers + sync region (ws is poisoned each call)
    zero_kernel<<<144, b256, 0, stream>>>(ws, 36864);

    // 1) embedding -> x [2048,512]
    embed_kernel<<<(2048 * 512) / 256, b256, 0, stream>>>(ph, emb, ws + O_X);

    // 2) encoder xg = x@W_ih^T + b_ih  [2048,2048] per dir
    gemm(ws + O_X, w_ih_f, b_ih_f, ws + O_XGF, 2048, G4, HH, 0);
    gemm(ws + O_X, w_ih_b, b_ih_b, ws + O_XGB, 2048, G4, HH, 0);

    // 3) encoder scans: 4 groups (2 dir x 2 batch-half) x 16 wgs
    lstm_scan<<<64, b256, 0, stream>>>(ws + O_XGF, ws + O_XGB,
                                       w_hh_f, w_hh_b, b_hh_f, b_hh_b,
                                       ws + O_ENCH, ws + O_HF, ws + O_HB,
                                       cnts, TT, 2);

    // 4) proj([hf,hb]) -> enc [2048,512]
    cat_kernel<<<(2048 * 1024) / 256, b256, 0, stream>>>(ws + O_HF, ws + O_HB, ws + O_CAT);
    gemm(ws + O_CAT, proj_w, proj_b, ws + O_ENC, 2048, HH, 2 * HH, 0);

    // 5) duration predictor
    gemm(ws + O_ENC, dur_w1, dur_b1, ws + O_H1, 2048, HH, HH, 1);
    gemm(ws + O_H1, dur_w2, dur_b2, ws + O_H2, 2048, 256, HH, 1);
    dur3_kernel<<<8, b256, 0, stream>>>(ws + O_H2, dur_w3, dur_b3, ws + O_LOGDUR);

    // 6) length regulation
    length_reg_kernel<<<8, b256, 0, stream>>>(durs, kidx);
    expand_kernel<<<(8192 * 512) / 256, b256, 0, stream>>>(ws + O_ENC, kidx, ws + O_EXP);

    // 7) q_in = Linear(mel shifted) [8192,512]
    melin_kernel<<<(8192 * MELC + 255) / 256, b256, 0, stream>>>(mel, ws + O_MELIN);
    gemm(ws + O_MELIN, melin_w, melin_b, ws + O_QIN, 8192, HH, MELC, 0);

    // 8) q,k,v projections (attn_in_w rows: [wq;wk;wv])
    gemm(ws + O_QIN, attin_w,              attin_b,        ws + O_Q, 8192, HH, HH, 0);
    gemm(ws + O_EXP, attin_w + 512 * 512,  attin_b + 512,  ws + O_K, 8192, HH, HH, 0);
    gemm(ws + O_EXP, attin_w + 1024 * 512, attin_b + 1024, ws + O_V, 8192, HH, HH, 0);

    // 9) attention -> ctx; out projection -> attended
    attn_kernel<<<dim3(4, 64), b256, 0, stream>>>(ws + O_Q, ws + O_K, ws + O_V, kidx, ws + O_CTX);
    gemm(ws + O_CTX, atout_w, atout_b, ws + O_ATT, 8192, HH, HH, 0);

    // 10) decoder: dec_in = [q_in, attended]; xg = dec_in@W_ih^T + b_ih
    decin_kernel<<<(8192 * 1024) / 256, b256, 0, stream>>>(ws + O_QIN, ws + O_ATT, ws + O_DECIN);
    gemm(ws + O_DECIN, dec_wih, dec_bih, ws + O_XGD, 8192, G4, 2 * HH, 0);

    // 11) decoder scan: 2 groups (batch halves) x 16 wgs
    lstm_scan<<<32, b256, 0, stream>>>(ws + O_XGD, ws + O_XGD,
                                       dec_whh, dec_whh, dec_bhh, dec_bhh,
                                       ws + O_DECH, ws + O_HDEC, ws + O_HDEC,
                                       cnts + 6144, TM, 1);

    // 12) mel projection + pack outputs
    gemm(ws + O_HDEC, melo_w, melo_b, ws + O_MELF, 8192, MELC, HH, 0);
    finalize_kernel<<<(BB * TM * MELC + BB * TT + 255) / 256, b256, 0, stream>>>(
        ws + O_MELF, ws + O_LOGDUR, (float*)d_out);
}

// Round 10
// 16383.981 us; speedup vs baseline: 1.0521x; 1.0521x over previous
//
#include <hip/hip_runtime.h>

// ---------------------------------------------------------------------------
// KokoroModel: emb -> biLSTM enc -> proj -> dur MLP -> length-regulate ->
//              MHA (teacher-forced) -> dec LSTM -> mel proj
// B=8, T_TEXT=256, T_MEL=1024, H=512, MEL=80, NH=8, HD=64 — all fp32.
// Round 10: barrier-free tagged h-exchange. Producer stores (h0,h1,tag,pad)
// as ONE dwordx4 sc1; consumer staging loads double as the poll (tag check
// embedded). 4-deep slot rotation replaces the ping-pong + barrier (skew<=1
// by the tag dependency). r7's 32-wg/group compute layout (no r9 spills).
// ---------------------------------------------------------------------------

typedef unsigned short u16;
typedef unsigned int u32;
typedef float f4 __attribute__((ext_vector_type(4)));

#define BB 8
#define TT 256
#define TM 1024
#define HH 512
#define MELC 80
#define G4 2048   // 4*H

__device__ __forceinline__ float sigmoidf_(float x) { return 1.f / (1.f + __expf(-x)); }
__device__ __forceinline__ float tanh_fast(float x) {
    float e = __expf(2.f * x);
    return 1.f - 2.f / (e + 1.f);
}

// ------------------------- workspace layout (floats) -----------------------
// O_SCAN: tagged h slots. Per group: 4 rot-slots x 2048 pair-slots x 4 floats
//         = 32768. enc g0 @0, enc g1 @32768, dec @65536. Total 98304.
#define O_SCAN    0u
#define O_LOGDUR  98304u
#define O_KIDX    100352u           /* 8192 ints */
#define O_ENC     108544u           /* 2048x512 -> ends 1157120 */
#define O_R1      1157120u          /* 4M: hf|hb|cat -> exp -> ctx */
#define O_ATT     5351424u          /* 4M attended */
#define O_QIN     9545728u          /* 4M q_in */
#define O_BIG2    13740032u         /* 8M: q|k -> dec_in -> h_dec|mel_f */
#define O_BIG1    22128640u         /* 16.8M: xg_f|xg_b|x -> h1|h2|v|mel_in -> xg_dec */
// sub-offsets
#define O_HF      (O_R1)
#define O_HB      (O_R1 + 1048576u)
#define O_CAT     (O_R1 + 2097152u)
#define O_EXP     (O_R1)
#define O_CTX     (O_R1)
#define O_Q       (O_BIG2)
#define O_K       (O_BIG2 + 4194304u)
#define O_DECIN   (O_BIG2)
#define O_HDEC    (O_BIG2)
#define O_MELF    (O_BIG2 + 4194304u)
#define O_XGF     (O_BIG1)
#define O_XGB     (O_BIG1 + 4194304u)
#define O_X       (O_BIG1 + 8388608u)
#define O_H1      (O_BIG1 + 8388608u)
#define O_H2      (O_BIG1 + 9437184u)
#define O_V       (O_BIG1 + 10485760u)
#define O_MELIN   (O_BIG1 + 14680064u)
#define O_XGD     (O_BIG1)

// ---------------------------------------------------------------------------
__global__ __launch_bounds__(256) void zero_kernel(float* p, int n) {
    int i = blockIdx.x * 256 + threadIdx.x;
    if (i < n) p[i] = 0.f;
}

__global__ __launch_bounds__(256) void embed_kernel(const int* idx, const float* emb, float* x) {
    int i = blockIdx.x * 256 + threadIdx.x;      // over 2048*512
    int tok = i >> 9, h = i & 511;
    x[i] = emb[(size_t)idx[tok] * HH + h];
}

// C[M,N] = act(A[M,K] @ W[N,K]^T + bias[N]);  all fp32.
// 128x128 tile, BK=16, 256 threads, 8x8 micro-tile in 2x2 float4 fragments.
template <int ACT>
__global__ __launch_bounds__(256) void gemm_bt(const float* __restrict__ A,
                                               const float* __restrict__ W,
                                               const float* __restrict__ bias,
                                               float* __restrict__ C,
                                               int M, int N, int K) {
    __shared__ float As[16][132];
    __shared__ float Ws[16][132];
    const int bm = blockIdx.y * 128, bn = blockIdx.x * 128;
    const int tid = threadIdx.x;
    const int tx = tid & 15, ty = tid >> 4;
    float acc[64];
#pragma unroll
    for (int i = 0; i < 64; i++) acc[i] = 0.f;

    for (int k0 = 0; k0 < K; k0 += 16) {
#pragma unroll
        for (int q = 0; q < 2; q++) {
            int fid = tid * 2 + q;               // 0..511
            int m = fid >> 2, kq = (fid & 3) << 2;
            float4 va = *(const float4*)(A + (size_t)(bm + m) * K + k0 + kq);
            As[kq + 0][m] = va.x; As[kq + 1][m] = va.y;
            As[kq + 2][m] = va.z; As[kq + 3][m] = va.w;
            float4 vw = make_float4(0.f, 0.f, 0.f, 0.f);
            if (bn + m < N) vw = *(const float4*)(W + (size_t)(bn + m) * K + k0 + kq);
            Ws[kq + 0][m] = vw.x; Ws[kq + 1][m] = vw.y;
            Ws[kq + 2][m] = vw.z; Ws[kq + 3][m] = vw.w;
        }
        __syncthreads();
#pragma unroll
        for (int kk = 0; kk < 16; kk++) {
            float4 a0 = *(const float4*)&As[kk][ty * 4];
            float4 a1 = *(const float4*)&As[kk][64 + ty * 4];
            float4 b0 = *(const float4*)&Ws[kk][tx * 4];
            float4 b1 = *(const float4*)&Ws[kk][64 + tx * 4];
            float av[8] = {a0.x, a0.y, a0.z, a0.w, a1.x, a1.y, a1.z, a1.w};
            float bv[8] = {b0.x, b0.y, b0.z, b0.w, b1.x, b1.y, b1.z, b1.w};
#pragma unroll
            for (int ih = 0; ih < 2; ih++)
#pragma unroll
                for (int ii = 0; ii < 4; ii++) {
                    float a = av[ih * 4 + ii];
#pragma unroll
                    for (int jh = 0; jh < 2; jh++)
#pragma unroll
                        for (int jjv = 0; jjv < 4; jjv++)
                            acc[(ih * 2 + jh) * 16 + ii * 4 + jjv] =
                                fmaf(a, bv[jh * 4 + jjv], acc[(ih * 2 + jh) * 16 + ii * 4 + jjv]);
                }
        }
        __syncthreads();
    }
#pragma unroll
    for (int ih = 0; ih < 2; ih++)
#pragma unroll
        for (int jh = 0; jh < 2; jh++) {
            int n = bn + jh * 64 + tx * 4;
            if (n >= N) continue;
            float4 bb = make_float4(0.f, 0.f, 0.f, 0.f);
            if (bias) bb = *(const float4*)(bias + n);
#pragma unroll
            for (int ii = 0; ii < 4; ii++) {
                int m = bm + ih * 64 + ty * 4 + ii;
                float4 o;
                o.x = acc[(ih * 2 + jh) * 16 + ii * 4 + 0] + bb.x;
                o.y = acc[(ih * 2 + jh) * 16 + ii * 4 + 1] + bb.y;
                o.z = acc[(ih * 2 + jh) * 16 + ii * 4 + 2] + bb.z;
                o.w = acc[(ih * 2 + jh) * 16 + ii * 4 + 3] + bb.w;
                if (ACT == 1) {
                    o.x = fmaxf(o.x, 0.f); o.y = fmaxf(o.y, 0.f);
                    o.z = fmaxf(o.z, 0.f); o.w = fmaxf(o.w, 0.f);
                }
                *(float4*)(C + (size_t)m * N + n) = o;
            }
        }
}

// ---------------------------------------------------------------------------
// Persistent barrier-free LSTM scan with tagged h exchange. 32 wgs/group; wg
// owns 16 j x 4 gates x all 8 batches (r7 layout, W_hh in VGPRs).
// Slot = (h_even, h_odd, tag, pad) 16B. Producer at step t writes rot t&3
// with tag t+1 (single dwordx4 sc1, no ordering waits). Consumer at step t
// poll-loads rot (t+3)&3 until all tags >= t. 4-deep rotation is safe:
// tag dependency bounds inter-wg skew to 1 step.
__global__ __launch_bounds__(256, 1) void lstm_scan(
    const float* __restrict__ xg0, const float* __restrict__ xg1,
    const float* __restrict__ whh0, const float* __restrict__ whh1,
    const float* __restrict__ bhh0, const float* __restrict__ bhh1,
    float* hbuf, float* hout0, float* hout1, int T, int ndir) {
    const int wg = blockIdx.x;
    const int group = wg >> 5;                   // dir (or 0)
    const int wgi = wg & 31;
    const int dir = (ndir == 2) ? group : 0;
    const float* xg  = dir ? xg1 : xg0;
    const float* whh = dir ? whh1 : whh0;
    const float* bhh = dir ? bhh1 : bhh0;
    float* hout = dir ? hout1 : hout0;
    float* hb = hbuf + group * 32768;            // [4 rot][2048 slots][4]

    const int wave = threadIdx.x >> 6;
    const int lane = threadIdx.x & 63;
    const int gate = lane & 3;
    const int ks = lane >> 2;                    // k-slice of 32
    const int jq = wgi * 16 + wave * 4;

    // weights: wv[jj][i4] = W_hh[gate*512 + jq+jj][ks*32 + i4*4 ..+4)
    float4 wv[4][8];
#pragma unroll
    for (int jj = 0; jj < 4; jj++) {
        const float4* wp = (const float4*)(whh + (size_t)(gate * HH + jq + jj) * HH + ks * 32);
#pragma unroll
        for (int i = 0; i < 8; i++) wv[jj][i] = wp[i];
    }
    float xb0 = bhh[gate * HH + jq + 0];
    float xb1 = bhh[gate * HH + jq + 1];
    float xb2 = bhh[gate * HH + jq + 2];
    float xb3 = bhh[gate * HH + jq + 3];
    float c_ = 0.f;                              // owner-lane cell state
    float hw_mine = 0.f;

    __shared__ float hs[4096];                   // staged h, bank-rotated

    // prefetch xg for t=0
    float4 xgv[8];
    if (ks == 0) {
        const int te0 = dir ? (T - 1) : 0;
#pragma unroll
        for (int b = 0; b < 8; b++)
            xgv[b] = *(const float4*)(xg + (size_t)(b * T + te0) * G4 + gate * HH + jq);
    }

    for (int t = 0; t < T; t++) {
        const int te = dir ? (T - 1 - t) : t;
        const int need = t;                      // tag written at t-1 is t
        // 1) poll+stage: 8 tagged slots per thread; loads ARE the barrier
        const float* sb = hb + ((t + 3) & 3) * 8192;
        f4 hv[8];
        int it = 0;
        while (true) {
#pragma unroll
            for (int q = 0; q < 8; q++) {
                const float* ap = sb + ((q * 256 + threadIdx.x) << 2);
                asm volatile("global_load_dwordx4 %0, %1, off sc0 sc1"
                             : "=v"(hv[q]) : "v"(ap) : "memory");
            }
            __builtin_amdgcn_s_waitcnt(0);
            bool ok = true;
#pragma unroll
            for (int q = 0; q < 8; q++) ok &= (__float_as_int(hv[q].z) >= need);
            if (__ballot(!ok) == 0ull) break;
            __builtin_amdgcn_s_sleep(1);
            if (++it > (1 << 22)) break;         // safety valve
        }
        // 2) wait for other waves to finish previous compute, then fill LDS
        __syncthreads();
#pragma unroll
        for (int q = 0; q < 8; q++) {
            int slot = q * 256 + threadIdx.x;    // 0..2047
            int b = slot >> 8, j0 = (slot & 255) << 1;
            int blk = j0 >> 5, off = j0 & 31;
            int rot = (off + (blk << 2)) & 31;   // off even -> rot even <= 30
            hs[b * HH + blk * 32 + rot]     = hv[q].x;
            hs[b * HH + blk * 32 + rot + 1] = hv[q].y;
        }
        __syncthreads();

        // 3) compute
#pragma unroll
        for (int b = 0; b < 8; b++) {
            float a0, a1, a2, a3;
            if (ks == 0) {
                a0 = xgv[b].x + xb0; a1 = xgv[b].y + xb1;
                a2 = xgv[b].z + xb2; a3 = xgv[b].w + xb3;
            } else { a0 = a1 = a2 = a3 = 0.f; }
#pragma unroll
            for (int i4 = 0; i4 < 8; i4++) {
                const float4 h4 = *(const float4*)
                    &hs[b * HH + ks * 32 + (((i4 + ks) & 7) << 2)];
                a0 = fmaf(wv[0][i4].x, h4.x, a0); a0 = fmaf(wv[0][i4].y, h4.y, a0);
                a0 = fmaf(wv[0][i4].z, h4.z, a0); a0 = fmaf(wv[0][i4].w, h4.w, a0);
                a1 = fmaf(wv[1][i4].x, h4.x, a1); a1 = fmaf(wv[1][i4].y, h4.y, a1);
                a1 = fmaf(wv[1][i4].z, h4.z, a1); a1 = fmaf(wv[1][i4].w, h4.w, a1);
                a2 = fmaf(wv[2][i4].x, h4.x, a2); a2 = fmaf(wv[2][i4].y, h4.y, a2);
                a2 = fmaf(wv[2][i4].z, h4.z, a2); a2 = fmaf(wv[2][i4].w, h4.w, a2);
                a3 = fmaf(wv[3][i4].x, h4.x, a3); a3 = fmaf(wv[3][i4].y, h4.y, a3);
                a3 = fmaf(wv[3][i4].z, h4.z, a3); a3 = fmaf(wv[3][i4].w, h4.w, a3);
            }
            a0 += __shfl_xor(a0, 4);  a1 += __shfl_xor(a1, 4);
            a2 += __shfl_xor(a2, 4);  a3 += __shfl_xor(a3, 4);
            a0 += __shfl_xor(a0, 8);  a1 += __shfl_xor(a1, 8);
            a2 += __shfl_xor(a2, 8);  a3 += __shfl_xor(a3, 8);
            a0 += __shfl_xor(a0, 16); a1 += __shfl_xor(a1, 16);
            a2 += __shfl_xor(a2, 16); a3 += __shfl_xor(a3, 16);
            a0 += __shfl_xor(a0, 32); a1 += __shfl_xor(a1, 32);
            a2 += __shfl_xor(a2, 32); a3 += __shfl_xor(a3, 32);
            const int base = 4 * b;
            float gi_ = 0.f, gf_ = 0.f, gg_ = 0.f, go_ = 0.f;
#pragma unroll
            for (int jj = 0; jj < 4; jj++) {
                float a = (jj == 0) ? a0 : (jj == 1) ? a1 : (jj == 2) ? a2 : a3;
                float g0 = __shfl(a, base + 0);
                float g1 = __shfl(a, base + 1);
                float g2 = __shfl(a, base + 2);
                float g3 = __shfl(a, base + 3);
                if (lane == base + jj) { gi_ = g0; gf_ = g1; gg_ = g2; go_ = g3; }
            }
            if ((lane >> 2) == b) {
                float i_ = sigmoidf_(gi_), f_ = sigmoidf_(gf_);
                float G_ = tanh_fast(gg_), o_ = sigmoidf_(go_);
                c_ = f_ * c_ + i_ * G_;
                hw_mine = o_ * tanh_fast(c_);
            }
        }
        // 4) producer: tagged pair store (fire-and-forget sc1) + hout
        float hpart = __shfl_xor(hw_mine, 1);
        if (lane < 32) {
            int b = lane >> 2, jj = lane & 3, j = jq + jj;
            hout[(size_t)(b * T + te) * HH + j] = hw_mine;
            if ((jj & 1) == 0) {
                f4 outv;
                outv.x = hw_mine; outv.y = hpart;
                outv.z = __int_as_float(t + 1); outv.w = 0.f;
                float* oa = hb + (t & 3) * 8192 + (size_t)(b * 256 + (j >> 1)) * 4;
                asm volatile("global_store_dwordx4 %0, %1, off sc0 sc1"
                             :: "v"(oa), "v"(outv) : "memory");
            }
        }
        // 5) prefetch next step's xg (completes under next poll)
        if (ks == 0 && t + 1 < T) {
            const int teN = dir ? (T - 2 - t) : (t + 1);
#pragma unroll
            for (int b = 0; b < 8; b++)
                xgv[b] = *(const float4*)(xg + (size_t)(b * T + teN) * G4 + gate * HH + jq);
        }
    }
}

__global__ __launch_bounds__(256) void cat_kernel(const float* hf, const float* hb, float* cat) {
    int i = blockIdx.x * 256 + threadIdx.x;      // over 2048*1024
    int row = i >> 10, h = i & 1023;
    cat[i] = (h < HH) ? hf[(size_t)row * HH + h] : hb[(size_t)row * HH + h - HH];
}

__global__ __launch_bounds__(256) void dur3_kernel(const float* __restrict__ h2,
                                                   const float* __restrict__ w,
                                                   const float* __restrict__ b, float* out) {
    int row = blockIdx.x * 256 + threadIdx.x;    // 2048
    float acc = b[0];
    const float* hp = h2 + (size_t)row * 256;
    for (int k = 0; k < 256; k++) acc += hp[k] * w[k];
    out[row] = acc;
}

// durations -> cumsum -> searchsorted index per mel position (-1 = pad)
__global__ __launch_bounds__(256) void length_reg_kernel(const float* __restrict__ dur, int* kidx) {
    int b = blockIdx.x;
    int t = threadIdx.x;
    __shared__ int cum[256];
    cum[t] = (int)rintf(dur[b * TT + t]);
    __syncthreads();
    for (int off = 1; off < 256; off <<= 1) {
        int val = (t >= off) ? cum[t - off] : 0;
        __syncthreads();
        cum[t] += val;
        __syncthreads();
    }
    int total = cum[255];
    for (int pos = t; pos < TM; pos += 256) {
        int lo = 0, hi = 256;
        while (lo < hi) {
            int mid = (lo + hi) >> 1;
            if (cum[mid] <= pos) lo = mid + 1; else hi = mid;
        }
        int idx = (pos < total) ? ((lo < 255) ? lo : 255) : -1;
        kidx[b * TM + pos] = idx;
    }
}

__global__ __launch_bounds__(256) void expand_kernel(const float* __restrict__ enc,
                                                     const int* __restrict__ kidx, float* exp_) {
    int i = blockIdx.x * 256 + threadIdx.x;      // over 8192*512
    int row = i >> 9, h = i & 511;               // row = b*1024 + pos
    int b = row >> 10;
    int id = kidx[row];
    exp_[i] = (id >= 0) ? enc[(size_t)(b * TT + id) * HH + h] : 0.f;
}

__global__ __launch_bounds__(256) void melin_kernel(const float* __restrict__ mel, float* mel_in) {
    int i = blockIdx.x * 256 + threadIdx.x;      // over 8192*80
    if (i >= BB * TM * MELC) return;
    int row = i / MELC, cc = i - row * MELC;
    int b = row >> 10, tpos = row & 1023;
    mel_in[i] = (tpos == 0) ? 0.f : mel[(size_t)(b * TM + tpos - 1) * MELC + cc];
}

// Flash-style MHA: one q-row per thread; K/V tiles (32x64) in LDS.
__global__ __launch_bounds__(256) void attn_kernel(const float* __restrict__ q,
                                                   const float* __restrict__ k,
                                                   const float* __restrict__ v,
                                                   const int* __restrict__ kidx,
                                                   float* __restrict__ ctx) {
    const int bh = blockIdx.y;
    const int b = bh >> 3, h = bh & 7;
    const int qrow = blockIdx.x * 256 + threadIdx.x;
    __shared__ float Ks[32][64];
    __shared__ float Vs[32][64];
    __shared__ float spad[32];

    float qr[64], acc[64];
    const float* qp = q + (size_t)(b * TM + qrow) * HH + h * 64;
#pragma unroll
    for (int d = 0; d < 64; d++) qr[d] = qp[d] * 0.125f;
#pragma unroll
    for (int d = 0; d < 64; d++) acc[d] = 0.f;
    float m = -1e30f, l = 0.f;

    for (int k0 = 0; k0 < TM; k0 += 32) {
        __syncthreads();
#pragma unroll
        for (int i = 0; i < 8; i++) {
            int idx = threadIdx.x + i * 256;     // 0..2047
            int r = idx >> 6, d = idx & 63;
            size_t off = (size_t)(b * TM + k0 + r) * HH + h * 64 + d;
            Ks[r][d] = k[off];
            Vs[r][d] = v[off];
        }
        if (threadIdx.x < 32)
            spad[threadIdx.x] = (kidx[b * TM + k0 + threadIdx.x] < 0) ? 1.f : 0.f;
        __syncthreads();
        for (int r = 0; r < 32; r++) {
            float s = 0.f;
#pragma unroll
            for (int d = 0; d < 64; d++) s += qr[d] * Ks[r][d];
            if (spad[r] != 0.f) s = -1e9f;
            float mn = fmaxf(m, s);
            float corr = __expf(m - mn);
            float p = __expf(s - mn);
            l = l * corr + p;
#pragma unroll
            for (int d = 0; d < 64; d++) acc[d] = acc[d] * corr + p * Vs[r][d];
            m = mn;
        }
    }
    float inv = 1.f / l;
    float* op = ctx + (size_t)(b * TM + qrow) * HH + h * 64;
#pragma unroll
    for (int d = 0; d < 64; d++) op[d] = acc[d] * inv;
}

__global__ __launch_bounds__(256) void decin_kernel(const float* q_in, const float* att, float* dec_in) {
    int i = blockIdx.x * 256 + threadIdx.x;      // over 8192*1024
    int row = i >> 10, h = i & 1023;
    dec_in[i] = (h < HH) ? q_in[(size_t)row * HH + h] : att[(size_t)row * HH + h - HH];
}

__global__ __launch_bounds__(256) void finalize_kernel(const float* melf, const float* logdur, float* out) {
    int i = blockIdx.x * 256 + threadIdx.x;
    if (i < BB * TM * MELC) out[i] = melf[i];
    else if (i < BB * TM * MELC + BB * TT) out[i] = logdur[i - BB * TM * MELC];
}

// ---------------------------------------------------------------------------
extern "C" void kernel_launch(void* const* d_in, const int* in_sizes, int n_in,
                              void* d_out, int out_size, void* d_ws, size_t ws_size,
                              hipStream_t stream) {
    const int*   ph      = (const int*)d_in[0];
    const float* mel     = (const float*)d_in[1];
    const float* durs    = (const float*)d_in[2];
    const float* emb     = (const float*)d_in[3];
    const float* w_ih_f  = (const float*)d_in[4];
    const float* w_hh_f  = (const float*)d_in[5];
    const float* b_ih_f  = (const float*)d_in[6];
    const float* b_hh_f  = (const float*)d_in[7];
    const float* w_ih_b  = (const float*)d_in[8];
    const float* w_hh_b  = (const float*)d_in[9];
    const float* b_ih_b  = (const float*)d_in[10];
    const float* b_hh_b  = (const float*)d_in[11];
    const float* proj_w  = (const float*)d_in[12];
    const float* proj_b  = (const float*)d_in[13];
    const float* dur_w1  = (const float*)d_in[14];
    const float* dur_b1  = (const float*)d_in[15];
    const float* dur_w2  = (const float*)d_in[16];
    const float* dur_b2  = (const float*)d_in[17];
    const float* dur_w3  = (const float*)d_in[18];
    const float* dur_b3  = (const float*)d_in[19];
    const float* melin_w = (const float*)d_in[20];
    const float* melin_b = (const float*)d_in[21];
    const float* attin_w = (const float*)d_in[22];
    const float* attin_b = (const float*)d_in[23];
    const float* atout_w = (const float*)d_in[24];
    const float* atout_b = (const float*)d_in[25];
    const float* dec_wih = (const float*)d_in[26];
    const float* dec_whh = (const float*)d_in[27];
    const float* dec_bih = (const float*)d_in[28];
    const float* dec_bhh = (const float*)d_in[29];
    const float* melo_w  = (const float*)d_in[30];
    const float* melo_b  = (const float*)d_in[31];

    float* ws = (float*)d_ws;
    int*   kidx = (int*)(ws + O_KIDX);

    dim3 b256(256);
    auto gemm = [&](const float* A, const float* W, const float* bias, float* C,
                    int M, int N, int K, int act) {
        dim3 g((N + 127) / 128, (M + 127) / 128);
        if (act) gemm_bt<1><<<g, b256, 0, stream>>>(A, W, bias, C, M, N, K);
        else     gemm_bt<0><<<g, b256, 0, stream>>>(A, W, bias, C, M, N, K);
    };

    // 0) zero tagged-slot region (tags must start at 0; ws is poisoned)
    zero_kernel<<<384, b256, 0, stream>>>(ws + O_SCAN, 98304);

    // 1) embedding -> x [2048,512]
    embed_kernel<<<(2048 * 512) / 256, b256, 0, stream>>>(ph, emb, ws + O_X);

    // 2) encoder xg = x@W_ih^T + b_ih  [2048,2048] per dir
    gemm(ws + O_X, w_ih_f, b_ih_f, ws + O_XGF, 2048, G4, HH, 0);
    gemm(ws + O_X, w_ih_b, b_ih_b, ws + O_XGB, 2048, G4, HH, 0);

    // 3) encoder scans: fwd+bwd, 2 groups x 32 wgs, tagged exchange
    lstm_scan<<<64, b256, 0, stream>>>(ws + O_XGF, ws + O_XGB,
                                       w_hh_f, w_hh_b, b_hh_f, b_hh_b,
                                       ws + O_SCAN, ws + O_HF, ws + O_HB, TT, 2);

    // 4) proj([hf,hb]) -> enc [2048,512]
    cat_kernel<<<(2048 * 1024) / 256, b256, 0, stream>>>(ws + O_HF, ws + O_HB, ws + O_CAT);
    gemm(ws + O_CAT, proj_w, proj_b, ws + O_ENC, 2048, HH, 2 * HH, 0);

    // 5) duration predictor
    gemm(ws + O_ENC, dur_w1, dur_b1, ws + O_H1, 2048, HH, HH, 1);
    gemm(ws + O_H1, dur_w2, dur_b2, ws + O_H2, 2048, 256, HH, 1);
    dur3_kernel<<<8, b256, 0, stream>>>(ws + O_H2, dur_w3, dur_b3, ws + O_LOGDUR);

    // 6) length regulation
    length_reg_kernel<<<8, b256, 0, stream>>>(durs, kidx);
    expand_kernel<<<(8192 * 512) / 256, b256, 0, stream>>>(ws + O_ENC, kidx, ws + O_EXP);

    // 7) q_in = Linear(mel shifted) [8192,512]
    melin_kernel<<<(8192 * MELC + 255) / 256, b256, 0, stream>>>(mel, ws + O_MELIN);
    gemm(ws + O_MELIN, melin_w, melin_b, ws + O_QIN, 8192, HH, MELC, 0);

    // 8) q,k,v projections (attn_in_w rows: [wq;wk;wv])
    gemm(ws + O_QIN, attin_w,              attin_b,        ws + O_Q, 8192, HH, HH, 0);
    gemm(ws + O_EXP, attin_w + 512 * 512,  attin_b + 512,  ws + O_K, 8192, HH, HH, 0);
    gemm(ws + O_EXP, attin_w + 1024 * 512, attin_b + 1024, ws + O_V, 8192, HH, HH, 0);

    // 9) attention -> ctx; out projection -> attended
    attn_kernel<<<dim3(4, 64), b256, 0, stream>>>(ws + O_Q, ws + O_K, ws + O_V, kidx, ws + O_CTX);
    gemm(ws + O_CTX, atout_w, atout_b, ws + O_ATT, 8192, HH, HH, 0);

    // 10) decoder: dec_in = [q_in, attended]; xg = dec_in@W_ih^T + b_ih
    decin_kernel<<<(8192 * 1024) / 256, b256, 0, stream>>>(ws + O_QIN, ws + O_ATT, ws + O_DECIN);
    gemm(ws + O_DECIN, dec_wih, dec_bih, ws + O_XGD, 8192, G4, 2 * HH, 0);

    // 11) decoder scan: 1 group x 32 wgs, tagged exchange
    lstm_scan<<<32, b256, 0, stream>>>(ws + O_XGD, ws + O_XGD,
                                       dec_whh, dec_whh, dec_bhh, dec_bhh,
                                       ws + O_SCAN + 65536, ws + O_HDEC, ws + O_HDEC, TM, 1);

    // 12) mel projection + pack outputs
    gemm(ws + O_HDEC, melo_w, melo_b, ws + O_MELF, 8192, MELC, HH, 0);
    finalize_kernel<<<(BB * TM * MELC + BB * TT + 255) / 256, b256, 0, stream>>>(
        ws + O_MELF, ws + O_LOGDUR, (float*)d_out);
}